// Round 4
// baseline (364.014 us; speedup 1.0000x reference)
//
#include <hip/hip_runtime.h>
#include <hip/hip_bf16.h>
#include <stdint.h>

#define B_SZ 8192
#define D_SZ 1024
#define O_SZ 1024
#define E_SZ 8

typedef __bf16 bf16_t;
typedef __bf16 bf16x8 __attribute__((ext_vector_type(8)));
typedef __bf16 bf16x4 __attribute__((ext_vector_type(4)));
typedef float  f32x4  __attribute__((ext_vector_type(4)));

// ---- fused prep ----
// blocks [0, 2048):    gating softmax(x@Wg+bg); write gates; write either
//                      A'_e = g_e * x (bf16, [E][B][D]) when prescale=1,
//                      or xb = bf16(x) when prescale=0.
// blocks [2048, 4096): We [E,D,O] fp32 -> WeT [E,O,D] bf16
__global__ __launch_bounds__(256) void prep_kernel(
    const float* __restrict__ x, const float* __restrict__ Wg,
    const float* __restrict__ bg, const float* __restrict__ We,
    float* __restrict__ gates, bf16_t* __restrict__ adst,
    bf16_t* __restrict__ WeT, int prescale) {
  __shared__ float tile[64][65];
  if (blockIdx.x < 2048) {
    const int w = threadIdx.x >> 6, lane = threadIdx.x & 63;
    const int b = blockIdx.x * 4 + w;
    const float* xr = x + (size_t)b * D_SZ;
    float acc[8];
#pragma unroll
    for (int e = 0; e < 8; ++e) acc[e] = 0.f;
    float xs[16];
#pragma unroll
    for (int it = 0; it < 4; ++it) {
      const int d = it * 256 + lane * 4;
      float4 xv = *(const float4*)(xr + d);
      xs[it * 4 + 0] = xv.x; xs[it * 4 + 1] = xv.y;
      xs[it * 4 + 2] = xv.z; xs[it * 4 + 3] = xv.w;
#pragma unroll
      for (int j = 0; j < 4; ++j) {
        const float4* wr = (const float4*)(Wg + (size_t)(d + j) * 8);
        float4 w0 = wr[0], w1 = wr[1];
        float xj = xs[it * 4 + j];
        acc[0] += xj * w0.x; acc[1] += xj * w0.y;
        acc[2] += xj * w0.z; acc[3] += xj * w0.w;
        acc[4] += xj * w1.x; acc[5] += xj * w1.y;
        acc[6] += xj * w1.z; acc[7] += xj * w1.w;
      }
    }
#pragma unroll
    for (int off = 32; off >= 1; off >>= 1) {
#pragma unroll
      for (int e = 0; e < 8; ++e) acc[e] += __shfl_xor(acc[e], off, 64);
    }
    // all lanes hold full sums after butterfly: softmax redundantly per lane
    float g[8];
#pragma unroll
    for (int e = 0; e < 8; ++e) g[e] = acc[e] + bg[e];
    float m = g[0];
#pragma unroll
    for (int e = 1; e < 8; ++e) m = fmaxf(m, g[e]);
    float s = 0.f;
#pragma unroll
    for (int e = 0; e < 8; ++e) { g[e] = __expf(g[e] - m); s += g[e]; }
    float inv = 1.0f / s;
#pragma unroll
    for (int e = 0; e < 8; ++e) g[e] *= inv;
    if (lane == 0) {
      float* gr = gates + (size_t)b * 8;
#pragma unroll
      for (int e = 0; e < 8; ++e) gr[e] = g[e];
    }
    if (prescale) {
#pragma unroll
      for (int e = 0; e < 8; ++e) {
        bf16_t* ar = adst + ((size_t)e * B_SZ + b) * D_SZ;
        const float ge = g[e];
#pragma unroll
        for (int it = 0; it < 4; ++it) {
          const int d = it * 256 + lane * 4;
          bf16x4 ov;
          ov[0] = (bf16_t)(ge * xs[it * 4 + 0]);
          ov[1] = (bf16_t)(ge * xs[it * 4 + 1]);
          ov[2] = (bf16_t)(ge * xs[it * 4 + 2]);
          ov[3] = (bf16_t)(ge * xs[it * 4 + 3]);
          *(bf16x4*)(ar + d) = ov;
        }
      }
    } else {
      bf16_t* ar = adst + (size_t)b * D_SZ;
#pragma unroll
      for (int it = 0; it < 4; ++it) {
        const int d = it * 256 + lane * 4;
        bf16x4 ov;
        ov[0] = (bf16_t)xs[it * 4 + 0]; ov[1] = (bf16_t)xs[it * 4 + 1];
        ov[2] = (bf16_t)xs[it * 4 + 2]; ov[3] = (bf16_t)xs[it * 4 + 3];
        *(bf16x4*)(ar + d) = ov;
      }
    }
  } else {
    const int tb = blockIdx.x - 2048;
    const int e = tb >> 8, rem = tb & 255;
    const int d0 = (rem >> 4) << 6, o0 = (rem & 15) << 6;
    const int tx = threadIdx.x & 63, ty = threadIdx.x >> 6;
    const float* src = We + (size_t)e * D_SZ * O_SZ;
#pragma unroll
    for (int i = 0; i < 16; ++i) {
      int d = ty + i * 4;
      tile[d][tx] = src[(size_t)(d0 + d) * O_SZ + o0 + tx];
    }
    __syncthreads();
    bf16_t* dst = WeT + (size_t)e * O_SZ * D_SZ;
#pragma unroll
    for (int i = 0; i < 16; ++i) {
      int o = ty + i * 4;
      dst[(size_t)(o0 + o) * D_SZ + d0 + tx] = (bf16_t)tile[tx][o];
    }
  }
}

// ---------------- fused expert GEMM ----------------
__device__ __forceinline__ void gload_lds16(const bf16_t* g, char* l) {
  __builtin_amdgcn_global_load_lds(
      (const __attribute__((address_space(1))) void*)g,
      (__attribute__((address_space(3))) void*)l, 16, 0, 0);
}

// PRESCALED=true: asrc = A' [E][B][D] (gate already folded in) -> single
//   64-AGPR accumulator across the whole expert group (m97-equivalent regs).
// PRESCALED=false: asrc = xb [B][D]; R1 dual-accumulator combine (fallback).
// gridDim.z expert groups; group 0 -> out, group 1 -> part1.
template <bool PRESCALED>
__global__ __launch_bounds__(256, 2) void moe_gemm(
    const bf16_t* __restrict__ asrc,
    const bf16_t* __restrict__ wet,   // [E, O, D] bf16
    const float* __restrict__ gates,  // [B, E]
    const float* __restrict__ be,     // [E, O]
    float* __restrict__ out,          // [B, O]
    float* __restrict__ part1)        // [B, O]
{
  __shared__ bf16_t lA[128 * 32];  // 8 KB, XOR-swizzled 16B granules
  __shared__ bf16_t lB[128 * 32];  // 8 KB
  __shared__ float  lG[128 * 9];   // stride 9: rows 4 apart -> different banks

  const int tid = threadIdx.x;
  const int b0 = blockIdx.y * 128;
  const int o0 = blockIdx.x * 128;
  const int ne = E_SZ / gridDim.z;
  const int e0 = blockIdx.z * ne;
  float* __restrict__ dst = blockIdx.z ? part1 : out;

  {  // stage gates, padded stride (ordered vs reads by first K-step barrier)
    const float* gsrc = gates + (size_t)b0 * 8;
#pragma unroll
    for (int i = 0; i < 4; ++i) {
      int idx = tid + 256 * i;
      lG[(idx >> 3) * 9 + (idx & 7)] = gsrc[idx];
    }
  }

  const int w = tid >> 6;
  const int lane = tid & 63;
  const int wm = (w >> 1) * 64;
  const int wn = (w & 1) * 64;
  const int m16 = lane & 15;
  const int q = lane >> 4;

  const int gi0 = tid, gi1 = tid + 256;
  const int ar0 = gi0 >> 2, ac0 = (((gi0 & 3) ^ ((gi0 >> 3) & 3)) * 8);
  const int ar1 = gi1 >> 2, ac1 = (((gi1 & 3) ^ ((gi1 >> 3) & 3)) * 8);
  char* lA0 = (char*)lA + w * 64 * 16;
  char* lA1 = (char*)lA + (256 + w * 64) * 16;
  char* lB0 = (char*)lB + w * 64 * 16;
  char* lB1 = (char*)lB + (256 + w * 64) * 16;

  f32x4 acc[4][4];
#pragma unroll
  for (int i = 0; i < 4; ++i)
#pragma unroll
    for (int j = 0; j < 4; ++j) acc[i][j] = f32x4{0.f, 0.f, 0.f, 0.f};

  f32x4 outAcc[4][4];  // dead (DCE'd) in PRESCALED mode
  if constexpr (!PRESCALED) {
#pragma unroll
    for (int i = 0; i < 4; ++i)
#pragma unroll
      for (int j = 0; j < 4; ++j) outAcc[i][j] = f32x4{0.f, 0.f, 0.f, 0.f};
  }

  for (int ei = 0; ei < ne; ++ei) {
    const int e = e0 + ei;
    const bf16_t* Abase = PRESCALED
        ? asrc + ((size_t)e * B_SZ + b0) * D_SZ
        : asrc + (size_t)b0 * D_SZ;
    const bf16_t* Bbase = wet + ((size_t)e * O_SZ + o0) * D_SZ;

    if constexpr (!PRESCALED) {
#pragma unroll
      for (int i = 0; i < 4; ++i)
#pragma unroll
        for (int j = 0; j < 4; ++j) acc[i][j] = f32x4{0.f, 0.f, 0.f, 0.f};
    }

    for (int kt = 0; kt < D_SZ / 32; ++kt) {
      const int kc = kt * 32;
      __syncthreads();  // previous iter's ds_reads done before overwrite
      gload_lds16(Abase + (size_t)ar0 * D_SZ + kc + ac0, lA0);
      gload_lds16(Abase + (size_t)ar1 * D_SZ + kc + ac1, lA1);
      gload_lds16(Bbase + (size_t)ar0 * D_SZ + kc + ac0, lB0);
      gload_lds16(Bbase + (size_t)ar1 * D_SZ + kc + ac1, lB1);
      __syncthreads();  // drains vmcnt(0) before barrier

      bf16x8 af[4], bfr[4];
#pragma unroll
      for (int i = 0; i < 4; ++i) {
        int r = wm + i * 16 + m16;
        int pg = (q ^ ((r >> 1) & 3)) * 8;
        af[i] = *(const bf16x8*)&lA[r * 32 + pg];
      }
#pragma unroll
      for (int j = 0; j < 4; ++j) {
        int r = wn + j * 16 + m16;
        int pg = (q ^ ((r >> 1) & 3)) * 8;
        bfr[j] = *(const bf16x8*)&lB[r * 32 + pg];
      }
#pragma unroll
      for (int i = 0; i < 4; ++i)
#pragma unroll
        for (int j = 0; j < 4; ++j)
          acc[i][j] = __builtin_amdgcn_mfma_f32_16x16x32_bf16(
              af[i], bfr[j], acc[i][j], 0, 0, 0);
    }

    if constexpr (!PRESCALED) {
      // outAcc += g[row,e] * (acc + be[e,col])
#pragma unroll
      for (int j = 0; j < 4; ++j) {
        float bec = be[e * O_SZ + o0 + wn + j * 16 + m16];
#pragma unroll
        for (int i = 0; i < 4; ++i) {
#pragma unroll
          for (int rg = 0; rg < 4; ++rg) {
            float gv = lG[(wm + i * 16 + q * 4 + rg) * 9 + e];
            outAcc[i][j][rg] += gv * (acc[i][j][rg] + bec);
          }
        }
      }
    }
  }

  if constexpr (PRESCALED) {
    // partial = acc (gates already folded into A') + sum_{e in grp} g_e*be
#pragma unroll
    for (int j = 0; j < 4; ++j) {
      const int col = o0 + wn + j * 16 + m16;
      float bec[4];
#pragma unroll
      for (int ei = 0; ei < 4; ++ei) bec[ei] = be[(e0 + ei) * O_SZ + col];
#pragma unroll
      for (int i = 0; i < 4; ++i) {
#pragma unroll
        for (int rg = 0; rg < 4; ++rg) {
          const int row = wm + i * 16 + q * 4 + rg;
          float v = acc[i][j][rg];
#pragma unroll
          for (int ei = 0; ei < 4; ++ei)
            v += lG[row * 9 + e0 + ei] * bec[ei];
          dst[(size_t)(b0 + row) * O_SZ + col] = v;
        }
      }
    }
  } else {
#pragma unroll
    for (int i = 0; i < 4; ++i)
#pragma unroll
      for (int rg = 0; rg < 4; ++rg) {
        float* orow = dst + (size_t)(b0 + wm + i * 16 + q * 4 + rg) * O_SZ
                      + o0 + wn + m16;
#pragma unroll
        for (int j = 0; j < 4; ++j) orow[j * 16] = outAcc[i][j][rg];
      }
  }
}

// ---------------- out += part1 ----------------
__global__ __launch_bounds__(256) void combine_kernel(
    float* __restrict__ out, const float* __restrict__ p1) {
  size_t i = (size_t)blockIdx.x * 256 + threadIdx.x;
  float4 a = ((const float4*)out)[i];
  float4 b = ((const float4*)p1)[i];
  a.x += b.x; a.y += b.y; a.z += b.z; a.w += b.w;
  ((float4*)out)[i] = a;
}

extern "C" void kernel_launch(void* const* d_in, const int* in_sizes, int n_in,
                              void* d_out, int out_size, void* d_ws, size_t ws_size,
                              hipStream_t stream) {
  const float* x  = (const float*)d_in[0];
  const float* Wg = (const float*)d_in[1];
  const float* bg = (const float*)d_in[2];
  const float* We = (const float*)d_in[3];
  const float* be = (const float*)d_in[4];
  float* out = (float*)d_out;

  char* ws = (char*)d_ws;
  const size_t GATES_B = (size_t)1 << 18;   // 256 KB
  const size_t WET_B   = (size_t)1 << 24;   // 16 MB
  const size_t P1_B    = (size_t)1 << 25;   // 32 MB
  const size_t AP_B    = (size_t)1 << 27;   // 128 MB

  float*  gates = (float*)ws;
  bf16_t* wet   = (bf16_t*)(ws + GATES_B);
  float*  p1    = (float*)(ws + GATES_B + WET_B);
  bf16_t* ap    = (bf16_t*)(ws + GATES_B + WET_B + P1_B);  // [E][B][D]
  bf16_t* xb    = (bf16_t*)(ws + GATES_B + WET_B);         // fallback layout

  const size_t need_full = GATES_B + WET_B + P1_B + AP_B;  // ~176.25 MB

  if (ws_size >= need_full) {
    prep_kernel<<<4096, 256, 0, stream>>>(x, Wg, bg, We, gates, ap, wet, 1);
    moe_gemm<true><<<dim3(O_SZ / 128, B_SZ / 128, 2), 256, 0, stream>>>(
        ap, wet, gates, be, out, p1);
    combine_kernel<<<(B_SZ * O_SZ / 4) / 256, 256, 0, stream>>>(out, p1);
  } else {
    prep_kernel<<<4096, 256, 0, stream>>>(x, Wg, bg, We, gates, xb, wet, 0);
    moe_gemm<false><<<dim3(O_SZ / 128, B_SZ / 128, 1), 256, 0, stream>>>(
        xb, wet, gates, be, out, p1);
  }
}

// Round 5
// 308.511 us; speedup vs baseline: 1.1799x; 1.1799x over previous
//
#include <hip/hip_runtime.h>
#include <hip/hip_bf16.h>
#include <stdint.h>

#define B_SZ 8192
#define D_SZ 1024
#define O_SZ 1024
#define E_SZ 8

typedef __bf16 bf16_t;
typedef __bf16 bf16x8 __attribute__((ext_vector_type(8)));
typedef __bf16 bf16x4 __attribute__((ext_vector_type(4)));
typedef float  f32x4  __attribute__((ext_vector_type(4)));

// ---- fused prep ----
// blocks [0, 2048):    gating softmax(x@Wg+bg) + x fp32->bf16 (4 rows/block)
// blocks [2048, 4096): We [E,D,O] fp32 -> WeT [E,O,D] bf16, vectorized:
//                      float4 reads (4/thread), bf16x8 16B stores (2/thread)
__global__ __launch_bounds__(256) void prep_kernel(
    const float* __restrict__ x, const float* __restrict__ Wg,
    const float* __restrict__ bg, const float* __restrict__ We,
    float* __restrict__ gates, bf16_t* __restrict__ xb,
    bf16_t* __restrict__ WeT) {
  __shared__ float tile[64][65];
  const int tid = threadIdx.x;
  if (blockIdx.x < 2048) {
    const int w = tid >> 6, lane = tid & 63;
    const int b = blockIdx.x * 4 + w;
    const float* xr = x + (size_t)b * D_SZ;
    float acc[8];
#pragma unroll
    for (int e = 0; e < 8; ++e) acc[e] = 0.f;
    float xs[16];
#pragma unroll
    for (int it = 0; it < 4; ++it) {
      const int d = it * 256 + lane * 4;
      float4 xv = *(const float4*)(xr + d);
      xs[it * 4 + 0] = xv.x; xs[it * 4 + 1] = xv.y;
      xs[it * 4 + 2] = xv.z; xs[it * 4 + 3] = xv.w;
#pragma unroll
      for (int j = 0; j < 4; ++j) {
        const float4* wr = (const float4*)(Wg + (size_t)(d + j) * 8);
        float4 w0 = wr[0], w1 = wr[1];
        float xj = xs[it * 4 + j];
        acc[0] += xj * w0.x; acc[1] += xj * w0.y;
        acc[2] += xj * w0.z; acc[3] += xj * w0.w;
        acc[4] += xj * w1.x; acc[5] += xj * w1.y;
        acc[6] += xj * w1.z; acc[7] += xj * w1.w;
      }
    }
#pragma unroll
    for (int off = 32; off >= 1; off >>= 1) {
#pragma unroll
      for (int e = 0; e < 8; ++e) acc[e] += __shfl_xor(acc[e], off, 64);
    }
    // all lanes hold full sums; softmax redundantly per lane
    float g[8];
#pragma unroll
    for (int e = 0; e < 8; ++e) g[e] = acc[e] + bg[e];
    float m = g[0];
#pragma unroll
    for (int e = 1; e < 8; ++e) m = fmaxf(m, g[e]);
    float s = 0.f;
#pragma unroll
    for (int e = 0; e < 8; ++e) { g[e] = __expf(g[e] - m); s += g[e]; }
    float inv = 1.0f / s;
    if (lane == 0) {
      float* gr = gates + (size_t)b * 8;
#pragma unroll
      for (int e = 0; e < 8; ++e) gr[e] = g[e] * inv;
    }
    // x -> bf16 (reuse registers)
    bf16_t* ar = xb + (size_t)b * D_SZ;
#pragma unroll
    for (int it = 0; it < 4; ++it) {
      const int d = it * 256 + lane * 4;
      bf16x4 ov;
      ov[0] = (bf16_t)xs[it * 4 + 0]; ov[1] = (bf16_t)xs[it * 4 + 1];
      ov[2] = (bf16_t)xs[it * 4 + 2]; ov[3] = (bf16_t)xs[it * 4 + 3];
      *(bf16x4*)(ar + d) = ov;
    }
  } else {
    const int tb = blockIdx.x - 2048;
    const int e = tb >> 8, rem = tb & 255;
    const int d0 = (rem >> 4) << 6, o0 = (rem & 15) << 6;
    const float* src = We + (size_t)e * D_SZ * O_SZ + (size_t)d0 * O_SZ + o0;
    // phase 1: 4 passes x 16 rows; thread -> (d, 4 consecutive o)
#pragma unroll
    for (int p = 0; p < 4; ++p) {
      const int d = p * 16 + (tid >> 4);
      const int o = (tid & 15) * 4;
      float4 v = *(const float4*)(src + (size_t)d * O_SZ + o);
      tile[d][o] = v.x; tile[d][o + 1] = v.y;
      tile[d][o + 2] = v.z; tile[d][o + 3] = v.w;
    }
    __syncthreads();
    // phase 2: 2 passes x 32 o-rows; thread -> (o, 8 consecutive d) bf16x8
    bf16_t* dstp = WeT + (size_t)e * O_SZ * D_SZ + (size_t)o0 * D_SZ + d0;
#pragma unroll
    for (int p = 0; p < 2; ++p) {
      const int o = p * 32 + (tid >> 3);
      const int d8 = (tid & 7) * 8;
      bf16x8 ov;
#pragma unroll
      for (int k = 0; k < 8; ++k) ov[k] = (bf16_t)tile[d8 + k][o];
      *(bf16x8*)(dstp + (size_t)o * D_SZ + d8) = ov;
    }
  }
}

// ---------------- fused expert GEMM + gate combine (R1 config) ----------------
__device__ __forceinline__ void gload_lds16(const bf16_t* g, char* l) {
  __builtin_amdgcn_global_load_lds(
      (const __attribute__((address_space(1))) void*)g,
      (__attribute__((address_space(3))) void*)l, 16, 0, 0);
}

__global__ __launch_bounds__(256, 2) void moe_gemm(
    const bf16_t* __restrict__ xb,    // [B, D] bf16
    const bf16_t* __restrict__ wet,   // [E, O, D] bf16
    const float* __restrict__ gates,  // [B, E]
    const float* __restrict__ be,     // [E, O]
    float* __restrict__ out)          // [B, O]
{
  __shared__ bf16_t lA[128 * 32];  // 8 KB, XOR-swizzled 16B granules
  __shared__ bf16_t lB[128 * 32];  // 8 KB, rows = o, cols = k
  __shared__ float  lG[128 * 8];   // 4 KB gates for this row-tile

  const int tid = threadIdx.x;
  const int b0 = blockIdx.y * 128;
  const int o0 = blockIdx.x * 128;

  {  // stage gates (barrier provided by first K-step barrier)
    const float* gsrc = gates + (size_t)b0 * 8;
#pragma unroll
    for (int i = 0; i < 4; ++i) lG[tid + 256 * i] = gsrc[tid + 256 * i];
  }

  const int w = tid >> 6;
  const int lane = tid & 63;
  const int wm = (w >> 1) * 64;
  const int wn = (w & 1) * 64;
  const int m16 = lane & 15;
  const int q = lane >> 4;

  const int gi0 = tid, gi1 = tid + 256;
  const int ar0 = gi0 >> 2, ac0 = (((gi0 & 3) ^ ((gi0 >> 3) & 3)) * 8);
  const int ar1 = gi1 >> 2, ac1 = (((gi1 & 3) ^ ((gi1 >> 3) & 3)) * 8);
  char* lA0 = (char*)lA + w * 64 * 16;
  char* lA1 = (char*)lA + (256 + w * 64) * 16;
  char* lB0 = (char*)lB + w * 64 * 16;
  char* lB1 = (char*)lB + (256 + w * 64) * 16;

  const bf16_t* Abase = xb + (size_t)b0 * D_SZ;

  f32x4 outAcc[4][4];
#pragma unroll
  for (int i = 0; i < 4; ++i)
#pragma unroll
    for (int j = 0; j < 4; ++j) outAcc[i][j] = f32x4{0.f, 0.f, 0.f, 0.f};

  for (int e = 0; e < E_SZ; ++e) {
    const bf16_t* Bbase = wet + ((size_t)e * O_SZ + o0) * D_SZ;
    f32x4 acc[4][4];
#pragma unroll
    for (int i = 0; i < 4; ++i)
#pragma unroll
      for (int j = 0; j < 4; ++j) acc[i][j] = f32x4{0.f, 0.f, 0.f, 0.f};

    for (int kt = 0; kt < D_SZ / 32; ++kt) {
      const int kc = kt * 32;
      __syncthreads();  // previous iter's ds_reads done before overwrite
      gload_lds16(Abase + (size_t)ar0 * D_SZ + kc + ac0, lA0);
      gload_lds16(Abase + (size_t)ar1 * D_SZ + kc + ac1, lA1);
      gload_lds16(Bbase + (size_t)ar0 * D_SZ + kc + ac0, lB0);
      gload_lds16(Bbase + (size_t)ar1 * D_SZ + kc + ac1, lB1);
      __syncthreads();  // compiler drains vmcnt(0) before this barrier

      bf16x8 af[4], bfr[4];
#pragma unroll
      for (int i = 0; i < 4; ++i) {
        int r = wm + i * 16 + m16;
        int pg = (q ^ ((r >> 1) & 3)) * 8;
        af[i] = *(const bf16x8*)&lA[r * 32 + pg];
      }
#pragma unroll
      for (int j = 0; j < 4; ++j) {
        int r = wn + j * 16 + m16;
        int pg = (q ^ ((r >> 1) & 3)) * 8;
        bfr[j] = *(const bf16x8*)&lB[r * 32 + pg];
      }
#pragma unroll
      for (int i = 0; i < 4; ++i)
#pragma unroll
        for (int j = 0; j < 4; ++j)
          acc[i][j] = __builtin_amdgcn_mfma_f32_16x16x32_bf16(
              af[i], bfr[j], acc[i][j], 0, 0, 0);
    }

    // outAcc += g[row,e] * (acc + be[e,col]); C layout: col=lane&15, row=q*4+reg
#pragma unroll
    for (int j = 0; j < 4; ++j) {
      float bec = be[e * O_SZ + o0 + wn + j * 16 + m16];
#pragma unroll
      for (int i = 0; i < 4; ++i) {
#pragma unroll
        for (int rg = 0; rg < 4; ++rg) {
          float gv = lG[(wm + i * 16 + q * 4 + rg) * 8 + e];
          outAcc[i][j][rg] += gv * (acc[i][j][rg] + bec);
        }
      }
    }
  }

#pragma unroll
  for (int i = 0; i < 4; ++i)
#pragma unroll
    for (int rg = 0; rg < 4; ++rg) {
      float* orow = out + (size_t)(b0 + wm + i * 16 + q * 4 + rg) * O_SZ
                    + o0 + wn + m16;
#pragma unroll
      for (int j = 0; j < 4; ++j) orow[j * 16] = outAcc[i][j][rg];
    }
}

extern "C" void kernel_launch(void* const* d_in, const int* in_sizes, int n_in,
                              void* d_out, int out_size, void* d_ws, size_t ws_size,
                              hipStream_t stream) {
  const float* x  = (const float*)d_in[0];
  const float* Wg = (const float*)d_in[1];
  const float* bg = (const float*)d_in[2];
  const float* We = (const float*)d_in[3];
  const float* be = (const float*)d_in[4];
  float* out = (float*)d_out;

  char* ws = (char*)d_ws;
  float*  gates = (float*)ws;                             // 256 KB
  bf16_t* xb    = (bf16_t*)(ws + (1 << 18));              // 16 MB
  bf16_t* wet   = (bf16_t*)(ws + (1 << 18) + (1 << 24));  // 16 MB
  // total ws use: ~32.25 MB

  prep_kernel<<<4096, 256, 0, stream>>>(x, Wg, bg, We, gates, xb, wet);
  moe_gemm<<<dim3(O_SZ / 128, B_SZ / 128), 256, 0, stream>>>(
      xb, wet, gates, be, out);
}